// Round 1
// baseline (1926.678 us; speedup 1.0000x reference)
//
#include <hip/hip_runtime.h>
#include <math.h>

#define NN 100000
#define NE 600000
#define DIM 128

// ---------------- degree / norm ----------------
__global__ void k_init(float* __restrict__ deg, float* __restrict__ pooled, int n) {
    int i = blockIdx.x * blockDim.x + threadIdx.x;
    if (i < n) deg[i] = 1.0f;            // self-loop contributes 1 to every degree
    if (i < DIM) pooled[i] = 0.0f;
}

__global__ void k_deg(const int* __restrict__ col, float* __restrict__ deg, int E) {
    int i = blockIdx.x * blockDim.x + threadIdx.x;
    if (i < E) atomicAdd(&deg[col[i]], 1.0f);
}

__global__ void k_rsqrt(float* __restrict__ deg, int n) {
    int i = blockIdx.x * blockDim.x + threadIdx.x;
    if (i < n) deg[i] = rsqrtf(deg[i]);   // deg >= 1 always (self-loops)
}

// ---------------- GEMM: H = elu?(X) @ W  (X: n x 128, W: 128 x 128) ----------------
// W fully staged in LDS (64 KB), 16-row x tile in LDS (8 KB) -> 72 KB, 2 blocks/CU.
// Each thread: 2 rows x 4 cols.
template <bool ELU>
__global__ __launch_bounds__(256) void k_gemm(const float* __restrict__ X,
                                              const float* __restrict__ W,
                                              float* __restrict__ H, int n) {
    __shared__ float Wl[DIM * DIM];    // [k][n] natural layout
    __shared__ float xs[16][DIM];

    for (int i = threadIdx.x; i < DIM * DIM / 4; i += 256)
        ((float4*)Wl)[i] = ((const float4*)W)[i];

    const int ct = threadIdx.x & 31;   // column group: cols 4*ct .. 4*ct+3
    const int rt = threadIdx.x >> 5;   // 0..7 ; rows rt and rt+8 of the tile
    const int c0 = ct * 4;

    for (int r0 = blockIdx.x * 16; r0 < n; r0 += gridDim.x * 16) {
        __syncthreads();  // guards W on first iter, xs reuse afterwards
        // stage 16 rows of X (zero-padded), applying ELU on load if requested
        for (int i = threadIdx.x; i < 16 * DIM / 4; i += 256) {
            int lr = i >> 5;        // local row (32 float4 per row)
            int k4 = i & 31;
            int r = r0 + lr;
            float4 v = make_float4(0.f, 0.f, 0.f, 0.f);
            if (r < n) v = ((const float4*)(X + (size_t)r * DIM))[k4];
            if (ELU) {
                v.x = v.x > 0.f ? v.x : expf(v.x) - 1.f;
                v.y = v.y > 0.f ? v.y : expf(v.y) - 1.f;
                v.z = v.z > 0.f ? v.z : expf(v.z) - 1.f;
                v.w = v.w > 0.f ? v.w : expf(v.w) - 1.f;
            }
            ((float4*)&xs[lr][0])[k4] = v;
        }
        __syncthreads();

        float4 accA = make_float4(0.f, 0.f, 0.f, 0.f);
        float4 accB = make_float4(0.f, 0.f, 0.f, 0.f);
        const int ra = rt, rb = rt + 8;
#pragma unroll 8
        for (int k4 = 0; k4 < 32; ++k4) {
            const float4 xa = *(const float4*)&xs[ra][k4 * 4];
            const float4 xb = *(const float4*)&xs[rb][k4 * 4];
            const float* wp = &Wl[(k4 * 4) * DIM + c0];
            float4 w;
            w = *(const float4*)(wp);
            accA.x += xa.x * w.x; accA.y += xa.x * w.y; accA.z += xa.x * w.z; accA.w += xa.x * w.w;
            accB.x += xb.x * w.x; accB.y += xb.x * w.y; accB.z += xb.x * w.z; accB.w += xb.x * w.w;
            w = *(const float4*)(wp + DIM);
            accA.x += xa.y * w.x; accA.y += xa.y * w.y; accA.z += xa.y * w.z; accA.w += xa.y * w.w;
            accB.x += xb.y * w.x; accB.y += xb.y * w.y; accB.z += xb.y * w.z; accB.w += xb.y * w.w;
            w = *(const float4*)(wp + 2 * DIM);
            accA.x += xa.z * w.x; accA.y += xa.z * w.y; accA.z += xa.z * w.z; accA.w += xa.z * w.w;
            accB.x += xb.z * w.x; accB.y += xb.z * w.y; accB.z += xb.z * w.z; accB.w += xb.z * w.w;
            w = *(const float4*)(wp + 3 * DIM);
            accA.x += xa.w * w.x; accA.y += xa.w * w.y; accA.z += xa.w * w.z; accA.w += xa.w * w.w;
            accB.x += xb.w * w.x; accB.y += xb.w * w.y; accB.z += xb.w * w.z; accB.w += xb.w * w.w;
        }
        const int rA = r0 + ra, rB = r0 + rb;
        if (rA < n) *(float4*)(H + (size_t)rA * DIM + c0) = accA;
        if (rB < n) *(float4*)(H + (size_t)rB * DIM + c0) = accB;
    }
}

// ---------------- AGG = b + H * dinv^2 (self-loop) ----------------
__global__ void k_selfbias(const float4* __restrict__ H4, const float* __restrict__ b,
                           const float* __restrict__ dinv, float4* __restrict__ A4, int n) {
    int i = blockIdx.x * blockDim.x + threadIdx.x;  // over n*32 float4s
    if (i < n * 32) {
        int node = i >> 5;
        int d4 = i & 31;
        float s = dinv[node];
        s = s * s;
        float4 h = H4[i];
        float4 bb = ((const float4*)b)[d4];
        float4 r;
        r.x = bb.x + h.x * s;
        r.y = bb.y + h.y * s;
        r.z = bb.z + h.z * s;
        r.w = bb.w + h.w * s;
        A4[i] = r;
    }
}

// ---------------- edge scatter: AGG[col] += H[row] * dinv[row]*dinv[col] ----------------
// one wave (64 lanes) per edge; each lane handles 2 consecutive dims
__global__ __launch_bounds__(256) void k_scatter(const float* __restrict__ H,
                                                 const int* __restrict__ rows,
                                                 const int* __restrict__ cols,
                                                 const float* __restrict__ dinv,
                                                 float* __restrict__ AGG, int E) {
    int gid = blockIdx.x * blockDim.x + threadIdx.x;
    int wid = gid >> 6;
    int lane = threadIdx.x & 63;
    int nw = (gridDim.x * blockDim.x) >> 6;
    for (int e = wid; e < E; e += nw) {
        int r = rows[e];
        int c = cols[e];
        float w = dinv[r] * dinv[c];
        float2 v = ((const float2*)(H + (size_t)r * DIM))[lane];
        float* a = AGG + (size_t)c * DIM + lane * 2;
        atomicAdd(a, v.x * w);
        atomicAdd(a + 1, v.y * w);
    }
}

// ---------------- mean pool (with fused ELU of last layer) ----------------
__global__ void k_pool(const float* __restrict__ X, float* __restrict__ pooled, int total) {
    int tid = blockIdx.x * blockDim.x + threadIdx.x;
    int stride = gridDim.x * blockDim.x;   // multiple of 128 by launch config
    float acc = 0.f;
    for (int i = tid; i < total; i += stride) {
        float v = X[i];
        v = v > 0.f ? v : expf(v) - 1.f;
        acc += v;
    }
    atomicAdd(&pooled[tid & 127], acc);
}

// ---------------- final linear: out = (pooled/N) @ lin_w + lin_b ----------------
__global__ void k_final(const float* __restrict__ pooled, const float* __restrict__ lw,
                        const float* __restrict__ lb, float* __restrict__ out) {
    int o = threadIdx.x;
    if (o < 24) {
        float acc = 0.f;
#pragma unroll 8
        for (int k = 0; k < DIM; ++k) acc += pooled[k] * lw[k * 24 + o];
        out[o] = acc * (1.0f / (float)NN) + lb[o];
    }
}

extern "C" void kernel_launch(void* const* d_in, const int* in_sizes, int n_in,
                              void* d_out, int out_size, void* d_ws, size_t ws_size,
                              hipStream_t stream) {
    const float* x  = (const float*)d_in[0];
    const int*   ei = (const int*)d_in[1];
    const float* W0 = (const float*)d_in[2];
    const float* b0 = (const float*)d_in[3];
    const float* W1 = (const float*)d_in[4];
    const float* b1 = (const float*)d_in[5];
    const float* W2 = (const float*)d_in[6];
    const float* b2 = (const float*)d_in[7];
    const float* lw = (const float*)d_in[8];
    const float* lb = (const float*)d_in[9];
    float* out = (float*)d_out;

    const int N = NN, E = NE;
    const int* rows = ei;        // edge_index[0] = sources (gather)
    const int* cols = ei + E;    // edge_index[1] = targets (scatter)

    float* ws = (float*)d_ws;
    float* dinv   = ws;                        // N floats (deg -> rsqrt in place)
    float* pooled = ws + 100352;               // 128 floats (aligned)
    float* H      = ws + 100608;               // N*128
    float* AGG    = H + (size_t)N * DIM;       // N*128

    k_init<<<(N + 255) / 256, 256, 0, stream>>>(dinv, pooled, N);
    k_deg<<<(E + 255) / 256, 256, 0, stream>>>(cols, dinv, E);
    k_rsqrt<<<(N + 255) / 256, 256, 0, stream>>>(dinv, N);

    const float* Ws[3] = {W0, W1, W2};
    const float* bs[3] = {b0, b1, b2};
    for (int l = 0; l < 3; ++l) {
        if (l == 0)
            k_gemm<false><<<512, 256, 0, stream>>>(x, Ws[l], H, N);
        else
            k_gemm<true><<<512, 256, 0, stream>>>(AGG, Ws[l], H, N);
        k_selfbias<<<(N * 32 + 255) / 256, 256, 0, stream>>>((const float4*)H, bs[l], dinv,
                                                             (float4*)AGG, N);
        k_scatter<<<4096, 256, 0, stream>>>(H, rows, cols, dinv, AGG, E);
    }
    k_pool<<<512, 256, 0, stream>>>(AGG, pooled, N * DIM);
    k_final<<<1, 64, 0, stream>>>(pooled, lw, lb, out);
}

// Round 2
// 612.927 us; speedup vs baseline: 3.1434x; 3.1434x over previous
//
#include <hip/hip_runtime.h>
#include <math.h>

#define NN 100000
#define NE 600000
#define DIM 128
#define SEG 1024
#define NSEG 98   // ceil(100000/1024)

// ---------------- zero counts + pooled ----------------
__global__ void k_zero(int* __restrict__ counts, float* __restrict__ pooled, int n1) {
    int i = blockIdx.x * blockDim.x + threadIdx.x;
    if (i < n1) counts[i] = 0;          // n1 = N+1
    if (i < DIM) pooled[i] = 0.0f;
}

// ---------------- histogram of targets ----------------
__global__ void k_count(const int* __restrict__ col, int* __restrict__ counts, int E) {
    int i = blockIdx.x * blockDim.x + threadIdx.x;
    if (i < E) atomicAdd(&counts[col[i]], 1);
}

// ---------------- dinv from counts (deg = counts + self-loop) ----------------
__global__ void k_rsqrt(const int* __restrict__ counts, float* __restrict__ dinv, int n) {
    int i = blockIdx.x * blockDim.x + threadIdx.x;
    if (i < n) dinv[i] = rsqrtf((float)counts[i] + 1.0f);
}

// ---------------- exclusive scan, phase 1: per-segment scan (in place) ----------------
__global__ __launch_bounds__(256) void k_scan1(int* __restrict__ data, int* __restrict__ segsum, int n) {
    __shared__ int s[256];
    const int t = threadIdx.x;
    const int base = blockIdx.x * SEG + t * 4;
    int v[4];
#pragma unroll
    for (int i = 0; i < 4; ++i) v[i] = (base + i < n) ? data[base + i] : 0;
    int tsum = v[0] + v[1] + v[2] + v[3];
    s[t] = tsum;
    __syncthreads();
    for (int off = 1; off < 256; off <<= 1) {
        int x = (t >= off) ? s[t - off] : 0;
        __syncthreads();
        s[t] += x;
        __syncthreads();
    }
    int run = s[t] - tsum;   // exclusive prefix of this thread within segment
#pragma unroll
    for (int i = 0; i < 4; ++i) {
        if (base + i < n) data[base + i] = run;
        run += v[i];
    }
    if (t == 255) segsum[blockIdx.x] = s[255];
}

// ---------------- scan phase 2: serial scan of 98 segment sums ----------------
__global__ void k_scan2(int* __restrict__ segsum, int* __restrict__ offsets, int n) {
    if (threadIdx.x == 0 && blockIdx.x == 0) {
        int run = 0;
        for (int i = 0; i < NSEG; ++i) {
            int t = segsum[i];
            segsum[i] = run;
            run += t;
        }
        offsets[n] = run;   // = E
    }
}

// ---------------- scan phase 3: add segment offsets; init cursor ----------------
__global__ __launch_bounds__(256) void k_scan3(int* __restrict__ offsets, const int* __restrict__ segsum,
                                               int* __restrict__ cursor, int n) {
    const int base = blockIdx.x * SEG + threadIdx.x * 4;
    const int so = segsum[blockIdx.x];
#pragma unroll
    for (int i = 0; i < 4; ++i) {
        if (base + i < n) {
            int o = offsets[base + i] + so;
            offsets[base + i] = o;
            cursor[base + i] = o;
        }
    }
}

// ---------------- CSR fill: adjacency + precomputed edge weights ----------------
__global__ void k_fill(const int* __restrict__ rows, const int* __restrict__ cols,
                       const float* __restrict__ dinv, int* __restrict__ cursor,
                       int* __restrict__ adj, float* __restrict__ wgt, int E) {
    int e = blockIdx.x * blockDim.x + threadIdx.x;
    if (e < E) {
        int r = rows[e];
        int c = cols[e];
        int pos = atomicAdd(&cursor[c], 1);
        adj[pos] = r;
        wgt[pos] = dinv[r] * dinv[c];
    }
}

// ---------------- GEMM: H = elu?(X) @ W  (X: n x 128, W: 128 x 128) ----------------
template <bool ELU>
__global__ __launch_bounds__(256) void k_gemm(const float* __restrict__ X,
                                              const float* __restrict__ W,
                                              float* __restrict__ H, int n) {
    __shared__ float Wl[DIM * DIM];    // [k][n] natural layout
    __shared__ float xs[16][DIM];

    for (int i = threadIdx.x; i < DIM * DIM / 4; i += 256)
        ((float4*)Wl)[i] = ((const float4*)W)[i];

    const int ct = threadIdx.x & 31;
    const int rt = threadIdx.x >> 5;
    const int c0 = ct * 4;

    for (int r0 = blockIdx.x * 16; r0 < n; r0 += gridDim.x * 16) {
        __syncthreads();
        for (int i = threadIdx.x; i < 16 * DIM / 4; i += 256) {
            int lr = i >> 5;
            int k4 = i & 31;
            int r = r0 + lr;
            float4 v = make_float4(0.f, 0.f, 0.f, 0.f);
            if (r < n) v = ((const float4*)(X + (size_t)r * DIM))[k4];
            if (ELU) {
                v.x = v.x > 0.f ? v.x : expf(v.x) - 1.f;
                v.y = v.y > 0.f ? v.y : expf(v.y) - 1.f;
                v.z = v.z > 0.f ? v.z : expf(v.z) - 1.f;
                v.w = v.w > 0.f ? v.w : expf(v.w) - 1.f;
            }
            ((float4*)&xs[lr][0])[k4] = v;
        }
        __syncthreads();

        float4 accA = make_float4(0.f, 0.f, 0.f, 0.f);
        float4 accB = make_float4(0.f, 0.f, 0.f, 0.f);
        const int ra = rt, rb = rt + 8;
#pragma unroll 8
        for (int k4 = 0; k4 < 32; ++k4) {
            const float4 xa = *(const float4*)&xs[ra][k4 * 4];
            const float4 xb = *(const float4*)&xs[rb][k4 * 4];
            const float* wp = &Wl[(k4 * 4) * DIM + c0];
            float4 w;
            w = *(const float4*)(wp);
            accA.x += xa.x * w.x; accA.y += xa.x * w.y; accA.z += xa.x * w.z; accA.w += xa.x * w.w;
            accB.x += xb.x * w.x; accB.y += xb.x * w.y; accB.z += xb.x * w.z; accB.w += xb.x * w.w;
            w = *(const float4*)(wp + DIM);
            accA.x += xa.y * w.x; accA.y += xa.y * w.y; accA.z += xa.y * w.z; accA.w += xa.y * w.w;
            accB.x += xb.y * w.x; accB.y += xb.y * w.y; accB.z += xb.y * w.z; accB.w += xb.y * w.w;
            w = *(const float4*)(wp + 2 * DIM);
            accA.x += xa.z * w.x; accA.y += xa.z * w.y; accA.z += xa.z * w.z; accA.w += xa.z * w.w;
            accB.x += xb.z * w.x; accB.y += xb.z * w.y; accB.z += xb.z * w.z; accB.w += xb.z * w.w;
            w = *(const float4*)(wp + 3 * DIM);
            accA.x += xa.w * w.x; accA.y += xa.w * w.y; accA.z += xa.w * w.z; accA.w += xa.w * w.w;
            accB.x += xb.w * w.x; accB.y += xb.w * w.y; accB.z += xb.w * w.z; accB.w += xb.w * w.w;
        }
        const int rA = r0 + ra, rB = r0 + rb;
        if (rA < n) *(float4*)(H + (size_t)rA * DIM + c0) = accA;
        if (rB < n) *(float4*)(H + (size_t)rB * DIM + c0) = accB;
    }
}

// ---------------- CSR aggregation (fused self-loop + bias), wave per node ----------------
__global__ __launch_bounds__(256) void k_agg(const float2* __restrict__ H2,
                                             const int* __restrict__ offsets,
                                             const int* __restrict__ adj,
                                             const float* __restrict__ wgt,
                                             const float* __restrict__ dinv,
                                             const float* __restrict__ b,
                                             float2* __restrict__ A2, int n) {
    const int wid = (blockIdx.x * blockDim.x + threadIdx.x) >> 6;
    const int lane = threadIdx.x & 63;
    if (wid >= n) return;
    const int c = wid;
    float s = dinv[c];
    s = s * s;
    float2 h = H2[(size_t)c * 64 + lane];
    float2 bb = ((const float2*)b)[lane];
    float2 acc;
    acc.x = bb.x + h.x * s;
    acc.y = bb.y + h.y * s;
    int j = offsets[c];
    const int end = offsets[c + 1];
    for (; j + 1 < end; j += 2) {
        int r0 = adj[j], r1 = adj[j + 1];
        float w0 = wgt[j], w1 = wgt[j + 1];
        float2 v0 = H2[(size_t)r0 * 64 + lane];
        float2 v1 = H2[(size_t)r1 * 64 + lane];
        acc.x += v0.x * w0 + v1.x * w1;
        acc.y += v0.y * w0 + v1.y * w1;
    }
    if (j < end) {
        int r = adj[j];
        float w = wgt[j];
        float2 v = H2[(size_t)r * 64 + lane];
        acc.x += v.x * w;
        acc.y += v.y * w;
    }
    A2[(size_t)c * 64 + lane] = acc;
}

// ---------------- mean pool (fused ELU of last layer) ----------------
__global__ void k_pool(const float* __restrict__ X, float* __restrict__ pooled, int total) {
    int tid = blockIdx.x * blockDim.x + threadIdx.x;
    int stride = gridDim.x * blockDim.x;
    float acc = 0.f;
    for (int i = tid; i < total; i += stride) {
        float v = X[i];
        v = v > 0.f ? v : expf(v) - 1.f;
        acc += v;
    }
    atomicAdd(&pooled[tid & 127], acc);
}

// ---------------- final linear ----------------
__global__ void k_final(const float* __restrict__ pooled, const float* __restrict__ lw,
                        const float* __restrict__ lb, float* __restrict__ out) {
    int o = threadIdx.x;
    if (o < 24) {
        float acc = 0.f;
#pragma unroll 8
        for (int k = 0; k < DIM; ++k) acc += pooled[k] * lw[k * 24 + o];
        out[o] = acc * (1.0f / (float)NN) + lb[o];
    }
}

extern "C" void kernel_launch(void* const* d_in, const int* in_sizes, int n_in,
                              void* d_out, int out_size, void* d_ws, size_t ws_size,
                              hipStream_t stream) {
    const float* x  = (const float*)d_in[0];
    const int*   ei = (const int*)d_in[1];
    const float* W0 = (const float*)d_in[2];
    const float* b0 = (const float*)d_in[3];
    const float* W1 = (const float*)d_in[4];
    const float* b1 = (const float*)d_in[5];
    const float* W2 = (const float*)d_in[6];
    const float* b2 = (const float*)d_in[7];
    const float* lw = (const float*)d_in[8];
    const float* lb = (const float*)d_in[9];
    float* out = (float*)d_out;

    const int N = NN, E = NE;
    const int* rows = ei;        // sources (gather)
    const int* cols = ei + E;    // targets (aggregate)

    float* ws = (float*)d_ws;
    float* dinv   = ws;                         // N
    float* pooled = ws + 100352;                // 128
    float* H      = ws + 100608;                // N*128
    float* AGG    = H + (size_t)N * DIM;        // N*128
    int*   offsets = (int*)(AGG + (size_t)N * DIM);  // N+1 (used as counts first), padded
    int*   cursor  = offsets + 100352;          // N
    int*   segsum  = cursor + 100352;           // 128
    int*   adj     = segsum + 128;              // E
    float* wgt     = (float*)(adj + E);         // E

    // ---- CSR build (once, amortized over 3 layers) ----
    k_zero<<<(N + 256) / 256, 256, 0, stream>>>(offsets, pooled, N + 1);
    k_count<<<(E + 255) / 256, 256, 0, stream>>>(cols, offsets, E);
    k_rsqrt<<<(N + 255) / 256, 256, 0, stream>>>(offsets, dinv, N);
    k_scan1<<<NSEG, 256, 0, stream>>>(offsets, segsum, N);
    k_scan2<<<1, 64, 0, stream>>>(segsum, offsets, N);
    k_scan3<<<NSEG, 256, 0, stream>>>(offsets, segsum, cursor, N);
    k_fill<<<(E + 255) / 256, 256, 0, stream>>>(rows, cols, dinv, cursor, adj, wgt, E);

    const float* Ws[3] = {W0, W1, W2};
    const float* bs[3] = {b0, b1, b2};
    for (int l = 0; l < 3; ++l) {
        if (l == 0)
            k_gemm<false><<<512, 256, 0, stream>>>(x, Ws[l], H, N);
        else
            k_gemm<true><<<512, 256, 0, stream>>>(AGG, Ws[l], H, N);
        k_agg<<<(N * 64 + 255) / 256, 256, 0, stream>>>((const float2*)H, offsets, adj, wgt,
                                                        dinv, bs[l], (float2*)AGG, N);
    }
    k_pool<<<512, 256, 0, stream>>>(AGG, pooled, N * DIM);
    k_final<<<1, 64, 0, stream>>>(pooled, lw, lb, out);
}

// Round 3
// 478.231 us; speedup vs baseline: 4.0288x; 1.2817x over previous
//
#include <hip/hip_runtime.h>
#include <math.h>

#define NN 100000
#define NE 600000
#define DIM 128
#define SEG 1024
#define NSEG 98   // ceil(100000/1024)

typedef __attribute__((ext_vector_type(8))) short short8;
typedef __attribute__((ext_vector_type(4))) float floatx4;

// bf16 helpers (RNE)
static __device__ __forceinline__ unsigned short f2bf(float f) {
    union { float f; unsigned u; } v; v.f = f;
    unsigned r = v.u + 0x7fffu + ((v.u >> 16) & 1u);
    return (unsigned short)(r >> 16);
}
static __device__ __forceinline__ float bflo(unsigned int p) {  // low bf16 of packed pair
    union { unsigned u; float f; } v; v.u = p << 16; return v.f;
}
static __device__ __forceinline__ float bfhi(unsigned int p) {  // high bf16
    union { unsigned u; float f; } v; v.u = p & 0xffff0000u; return v.f;
}

// ---------------- zero counts + pooled ----------------
__global__ void k_zero(int* __restrict__ counts, float* __restrict__ pooled, int n1) {
    int i = blockIdx.x * blockDim.x + threadIdx.x;
    if (i < n1) counts[i] = 0;
    if (i < DIM) pooled[i] = 0.0f;
}

__global__ void k_count(const int* __restrict__ col, int* __restrict__ counts, int E) {
    int i = blockIdx.x * blockDim.x + threadIdx.x;
    if (i < E) atomicAdd(&counts[col[i]], 1);
}

__global__ void k_rsqrt(const int* __restrict__ counts, float* __restrict__ dinv, int n) {
    int i = blockIdx.x * blockDim.x + threadIdx.x;
    if (i < n) dinv[i] = rsqrtf((float)counts[i] + 1.0f);
}

// ---------------- exclusive scan ----------------
__global__ __launch_bounds__(256) void k_scan1(int* __restrict__ data, int* __restrict__ segsum, int n) {
    __shared__ int s[256];
    const int t = threadIdx.x;
    const int base = blockIdx.x * SEG + t * 4;
    int v[4];
#pragma unroll
    for (int i = 0; i < 4; ++i) v[i] = (base + i < n) ? data[base + i] : 0;
    int tsum = v[0] + v[1] + v[2] + v[3];
    s[t] = tsum;
    __syncthreads();
    for (int off = 1; off < 256; off <<= 1) {
        int x = (t >= off) ? s[t - off] : 0;
        __syncthreads();
        s[t] += x;
        __syncthreads();
    }
    int run = s[t] - tsum;
#pragma unroll
    for (int i = 0; i < 4; ++i) {
        if (base + i < n) data[base + i] = run;
        run += v[i];
    }
    if (t == 255) segsum[blockIdx.x] = s[255];
}

__global__ void k_scan2(int* __restrict__ segsum, int* __restrict__ offsets, int n) {
    if (threadIdx.x == 0 && blockIdx.x == 0) {
        int run = 0;
        for (int i = 0; i < NSEG; ++i) { int t = segsum[i]; segsum[i] = run; run += t; }
        offsets[n] = run;
    }
}

__global__ __launch_bounds__(256) void k_scan3(int* __restrict__ offsets, const int* __restrict__ segsum,
                                               int* __restrict__ cursor, int n) {
    const int base = blockIdx.x * SEG + threadIdx.x * 4;
    const int so = segsum[blockIdx.x];
#pragma unroll
    for (int i = 0; i < 4; ++i) {
        if (base + i < n) {
            int o = offsets[base + i] + so;
            offsets[base + i] = o;
            cursor[base + i] = o;
        }
    }
}

__global__ void k_fill(const int* __restrict__ rows, const int* __restrict__ cols,
                       const float* __restrict__ dinv, int* __restrict__ cursor,
                       int* __restrict__ adj, float* __restrict__ wgt, int E) {
    int e = blockIdx.x * blockDim.x + threadIdx.x;
    if (e < E) {
        int r = rows[e];
        int c = cols[e];
        int pos = atomicAdd(&cursor[c], 1);
        adj[pos] = r;
        wgt[pos] = dinv[r] * dinv[c];
    }
}

// ---------------- W pack: fragment-order bf16 ----------------
// Wp[((ct*4+kk)*64 + L)*8 + j] = bf16( W[(kk*32 + (L>>4)*8 + j)*128 + ct*16 + (L&15)] )
__global__ void k_wpack(const float* __restrict__ W, unsigned short* __restrict__ Wp) {
    int e = blockIdx.x * 256 + threadIdx.x;   // 0..16383
    int j  = e & 7;
    int L  = (e >> 3) & 63;
    int kk = (e >> 9) & 3;
    int ct = e >> 11;
    int k = kk * 32 + (L >> 4) * 8 + j;
    int c = ct * 16 + (L & 15);
    Wp[e] = f2bf(W[k * DIM + c]);
}

// ---------------- MFMA GEMM: H(bf16) = A @ W ----------------
// block = 256 thr = 4 waves (2x2), tile 64 rows x 128 cols, K=128.
// B-frags in registers for whole kernel; A staged in LDS (padded stride 136).
template <bool A_IS_F32>
__global__ __launch_bounds__(256) void k_gemm(const void* __restrict__ Ain,
                                              const unsigned short* __restrict__ Wp,
                                              unsigned short* __restrict__ H, int n) {
    __shared__ __align__(16) unsigned short As[64][136];
    const int t = threadIdx.x;
    const int wid = t >> 6, lane = t & 63;
    const int wy = wid & 1, wx = wid >> 1;
    const int base = blockIdx.x * 64;

    // B fragments: 4 col-tiles x 4 k-steps, register-resident
    short8 Bf[4][4];
    {
        const short8* wp8 = (const short8*)Wp;
#pragma unroll
        for (int tt = 0; tt < 4; ++tt)
#pragma unroll
            for (int kk = 0; kk < 4; ++kk)
                Bf[tt][kk] = wp8[(((wx * 4 + tt) * 4 + kk) * 64) + lane];
    }

    // stage A tile -> LDS (convert to bf16 if fp32 input)
    if constexpr (A_IS_F32) {
        const float* A = (const float*)Ain;
#pragma unroll
        for (int it = 0; it < 8; ++it) {
            int idx = it * 256 + t;
            int row = idx >> 5, seg = idx & 31;       // 32 float4 per row
            int r = base + row;
            float4 v = make_float4(0.f, 0.f, 0.f, 0.f);
            if (r < n) v = ((const float4*)(A + (size_t)r * DIM))[seg];
            ushort4 o;
            o.x = f2bf(v.x); o.y = f2bf(v.y); o.z = f2bf(v.z); o.w = f2bf(v.w);
            *((ushort4*)&As[row][seg * 4]) = o;
        }
    } else {
        const unsigned short* A = (const unsigned short*)Ain;
#pragma unroll
        for (int it = 0; it < 4; ++it) {
            int idx = it * 256 + t;
            int row = idx >> 4, seg = idx & 15;       // 16 x (8 bf16) per row
            int r = base + row;
            uint4 v = make_uint4(0, 0, 0, 0);
            if (r < n) v = ((const uint4*)(A + (size_t)r * DIM))[seg];
            *((uint4*)&As[row][seg * 8]) = v;
        }
    }
    __syncthreads();

    floatx4 acc[2][4];
#pragma unroll
    for (int rs = 0; rs < 2; ++rs)
#pragma unroll
        for (int tt = 0; tt < 4; ++tt) acc[rs][tt] = (floatx4){0.f, 0.f, 0.f, 0.f};

    const int m = lane & 15, q = lane >> 4;
#pragma unroll
    for (int rs = 0; rs < 2; ++rs) {
        const int rbase = wy * 32 + rs * 16 + m;
        short8 Af[4];
#pragma unroll
        for (int kk = 0; kk < 4; ++kk)
            Af[kk] = *((const short8*)&As[rbase][kk * 32 + q * 8]);
#pragma unroll
        for (int kk = 0; kk < 4; ++kk)
#pragma unroll
            for (int tt = 0; tt < 4; ++tt)
                acc[rs][tt] = __builtin_amdgcn_mfma_f32_16x16x32_bf16(Af[kk], Bf[tt][kk],
                                                                     acc[rs][tt], 0, 0, 0);
    }
    __syncthreads();

    // D -> LDS (bf16), then coalesced copy-out
#pragma unroll
    for (int rs = 0; rs < 2; ++rs)
#pragma unroll
        for (int tt = 0; tt < 4; ++tt) {
            const int col = wx * 64 + tt * 16 + m;
            const int rowb = wy * 32 + rs * 16 + q * 4;
#pragma unroll
            for (int i = 0; i < 4; ++i)
                As[rowb + i][col] = f2bf(acc[rs][tt][i]);
        }
    __syncthreads();
#pragma unroll
    for (int it = 0; it < 4; ++it) {
        int idx = it * 256 + t;
        int row = idx >> 4, seg = idx & 15;
        int r = base + row;
        if (r < n)
            ((uint4*)(H + (size_t)r * DIM))[seg] = *((const uint4*)&As[row][seg * 8]);
    }
}

// ---------------- CSR aggregation (self-loop + bias + ELU), wave per node ----------------
__global__ __launch_bounds__(256) void k_agg(const unsigned short* __restrict__ H,
                                             const int* __restrict__ offsets,
                                             const int* __restrict__ adj,
                                             const float* __restrict__ wgt,
                                             const float* __restrict__ dinv,
                                             const float* __restrict__ b,
                                             unsigned short* __restrict__ AGG, int n) {
    const int wid = (blockIdx.x * blockDim.x + threadIdx.x) >> 6;
    const int lane = threadIdx.x & 63;
    if (wid >= n) return;
    const int c = wid;
    float s = dinv[c];
    s = s * s;
    unsigned int hv = *(const unsigned int*)(H + (size_t)c * DIM + lane * 2);
    float2 bb = ((const float2*)b)[lane];
    float ax = bb.x + bflo(hv) * s;
    float ay = bb.y + bfhi(hv) * s;
    int j = offsets[c];
    const int end = offsets[c + 1];
    for (; j + 1 < end; j += 2) {
        int r0 = adj[j], r1 = adj[j + 1];
        float w0 = wgt[j], w1 = wgt[j + 1];
        unsigned int v0 = *(const unsigned int*)(H + (size_t)r0 * DIM + lane * 2);
        unsigned int v1 = *(const unsigned int*)(H + (size_t)r1 * DIM + lane * 2);
        ax += bflo(v0) * w0 + bflo(v1) * w1;
        ay += bfhi(v0) * w0 + bfhi(v1) * w1;
    }
    if (j < end) {
        int r = adj[j];
        float w = wgt[j];
        unsigned int v = *(const unsigned int*)(H + (size_t)r * DIM + lane * 2);
        ax += bflo(v) * w;
        ay += bfhi(v) * w;
    }
    // ELU fused at store (AGG holds post-activation)
    ax = ax > 0.f ? ax : expf(ax) - 1.f;
    ay = ay > 0.f ? ay : expf(ay) - 1.f;
    unsigned int outv = (unsigned int)f2bf(ax) | ((unsigned int)f2bf(ay) << 16);
    *(unsigned int*)(AGG + (size_t)c * DIM + lane * 2) = outv;
}

// ---------------- mean pool (AGG already post-ELU) ----------------
__global__ void k_pool(const unsigned int* __restrict__ X2, float* __restrict__ pooled, int total2) {
    int tid = blockIdx.x * blockDim.x + threadIdx.x;
    int stride = gridDim.x * blockDim.x;    // multiple of 64
    float ax = 0.f, ay = 0.f;
    for (int i = tid; i < total2; i += stride) {
        unsigned int v = X2[i];
        ax += bflo(v);
        ay += bfhi(v);
    }
    int d = (tid & 63) * 2;
    atomicAdd(&pooled[d], ax);
    atomicAdd(&pooled[d + 1], ay);
}

__global__ void k_final(const float* __restrict__ pooled, const float* __restrict__ lw,
                        const float* __restrict__ lb, float* __restrict__ out) {
    int o = threadIdx.x;
    if (o < 24) {
        float acc = 0.f;
#pragma unroll 8
        for (int k = 0; k < DIM; ++k) acc += pooled[k] * lw[k * 24 + o];
        out[o] = acc * (1.0f / (float)NN) + lb[o];
    }
}

extern "C" void kernel_launch(void* const* d_in, const int* in_sizes, int n_in,
                              void* d_out, int out_size, void* d_ws, size_t ws_size,
                              hipStream_t stream) {
    const float* x  = (const float*)d_in[0];
    const int*   ei = (const int*)d_in[1];
    const float* W0 = (const float*)d_in[2];
    const float* b0 = (const float*)d_in[3];
    const float* W1 = (const float*)d_in[4];
    const float* b1 = (const float*)d_in[5];
    const float* W2 = (const float*)d_in[6];
    const float* b2 = (const float*)d_in[7];
    const float* lw = (const float*)d_in[8];
    const float* lb = (const float*)d_in[9];
    float* out = (float*)d_out;

    const int N = NN, E = NE;
    const int* rows = ei;        // sources (gather)
    const int* cols = ei + E;    // targets (aggregate)

    char* ws = (char*)d_ws;
    unsigned short* H   = (unsigned short*)ws;                      // 25,600,000 B
    unsigned short* AGG = (unsigned short*)(ws + 25600000);         // 25,600,000 B
    float* dinv    = (float*)(ws + 51200000);                       // 400,000 B
    float* pooled  = (float*)(ws + 51600000);                       // 512 B
    int*   offsets = (int*)(ws + 51600512);                         // 400,128 B (N+1)
    int*   cursor  = (int*)(ws + 52000640);                         // 400,000 B
    int*   segsum  = (int*)(ws + 52400640);                         // 512 B
    int*   adj     = (int*)(ws + 52401152);                         // 2,400,000 B
    float* wgt     = (float*)(ws + 54801152);                       // 2,400,000 B
    unsigned short* Wp0 = (unsigned short*)(ws + 57201152);         // 32,768 B each
    unsigned short* Wp1 = Wp0 + 16384;
    unsigned short* Wp2 = Wp1 + 16384;

    // ---- CSR build + W packing ----
    k_zero<<<(N + 256) / 256, 256, 0, stream>>>(offsets, pooled, N + 1);
    k_count<<<(E + 255) / 256, 256, 0, stream>>>(cols, offsets, E);
    k_rsqrt<<<(N + 255) / 256, 256, 0, stream>>>(offsets, dinv, N);
    k_scan1<<<NSEG, 256, 0, stream>>>(offsets, segsum, N);
    k_scan2<<<1, 64, 0, stream>>>(segsum, offsets, N);
    k_scan3<<<NSEG, 256, 0, stream>>>(offsets, segsum, cursor, N);
    k_fill<<<(E + 255) / 256, 256, 0, stream>>>(rows, cols, dinv, cursor, adj, wgt, E);
    k_wpack<<<64, 256, 0, stream>>>(W0, Wp0);
    k_wpack<<<64, 256, 0, stream>>>(W1, Wp1);
    k_wpack<<<64, 256, 0, stream>>>(W2, Wp2);

    const int gemm_grid = (N + 63) / 64;
    const unsigned short* Wps[3] = {Wp0, Wp1, Wp2};
    const float* bs[3] = {b0, b1, b2};
    for (int l = 0; l < 3; ++l) {
        if (l == 0)
            k_gemm<true><<<gemm_grid, 256, 0, stream>>>((const void*)x, Wps[l], H, N);
        else
            k_gemm<false><<<gemm_grid, 256, 0, stream>>>((const void*)AGG, Wps[l], H, N);
        k_agg<<<(N * 64 + 255) / 256, 256, 0, stream>>>(H, offsets, adj, wgt, dinv, bs[l], AGG, N);
    }
    k_pool<<<512, 256, 0, stream>>>((const unsigned int*)AGG, pooled, N * 64);
    k_final<<<1, 64, 0, stream>>>(pooled, lw, lb, out);
}

// Round 4
// 355.594 us; speedup vs baseline: 5.4182x; 1.3449x over previous
//
#include <hip/hip_runtime.h>
#include <math.h>

#define NN 100000
#define NE 600000
#define DIM 128
#define SEG 1024
#define NSEG 98   // ceil(100000/1024)
#define PBLK 2048 // pooled-agg grid

typedef __attribute__((ext_vector_type(8))) short short8;
typedef __attribute__((ext_vector_type(4))) float floatx4;

// bf16 helpers (RNE)
static __device__ __forceinline__ unsigned short f2bf(float f) {
    union { float f; unsigned u; } v; v.f = f;
    unsigned r = v.u + 0x7fffu + ((v.u >> 16) & 1u);
    return (unsigned short)(r >> 16);
}
static __device__ __forceinline__ float bflo(unsigned int p) {
    union { unsigned u; float f; } v; v.u = p << 16; return v.f;
}
static __device__ __forceinline__ float bfhi(unsigned int p) {
    union { unsigned u; float f; } v; v.u = p & 0xffff0000u; return v.f;
}

// ---------------- zero counts ----------------
__global__ void k_zero(int* __restrict__ counts, int n1) {
    int i = blockIdx.x * blockDim.x + threadIdx.x;
    if (i < n1) counts[i] = 0;
}

__global__ void k_count(const int* __restrict__ col, int* __restrict__ counts, int E) {
    int i = blockIdx.x * blockDim.x + threadIdx.x;
    if (i < E) atomicAdd(&counts[col[i]], 1);
}

__global__ void k_rsqrt(const int* __restrict__ counts, float* __restrict__ dinv, int n) {
    int i = blockIdx.x * blockDim.x + threadIdx.x;
    if (i < n) dinv[i] = rsqrtf((float)counts[i] + 1.0f);
}

// ---------------- exclusive scan ----------------
__global__ __launch_bounds__(256) void k_scan1(int* __restrict__ data, int* __restrict__ segsum, int n) {
    __shared__ int s[256];
    const int t = threadIdx.x;
    const int base = blockIdx.x * SEG + t * 4;
    int v[4];
#pragma unroll
    for (int i = 0; i < 4; ++i) v[i] = (base + i < n) ? data[base + i] : 0;
    int tsum = v[0] + v[1] + v[2] + v[3];
    s[t] = tsum;
    __syncthreads();
    for (int off = 1; off < 256; off <<= 1) {
        int x = (t >= off) ? s[t - off] : 0;
        __syncthreads();
        s[t] += x;
        __syncthreads();
    }
    int run = s[t] - tsum;
#pragma unroll
    for (int i = 0; i < 4; ++i) {
        if (base + i < n) data[base + i] = run;
        run += v[i];
    }
    if (t == 255) segsum[blockIdx.x] = s[255];
}

__global__ void k_scan2(int* __restrict__ segsum, int* __restrict__ offsets, int n) {
    if (threadIdx.x == 0 && blockIdx.x == 0) {
        int run = 0;
        for (int i = 0; i < NSEG; ++i) { int t = segsum[i]; segsum[i] = run; run += t; }
        offsets[n] = run;
    }
}

__global__ __launch_bounds__(256) void k_scan3(int* __restrict__ offsets, const int* __restrict__ segsum,
                                               int* __restrict__ cursor, int n) {
    const int base = blockIdx.x * SEG + threadIdx.x * 4;
    const int so = segsum[blockIdx.x];
#pragma unroll
    for (int i = 0; i < 4; ++i) {
        if (base + i < n) {
            int o = offsets[base + i] + so;
            offsets[base + i] = o;
            cursor[base + i] = o;
        }
    }
}

// ---------------- CSR fill: packed (adj, weight) int2 ----------------
__global__ void k_fill(const int* __restrict__ rows, const int* __restrict__ cols,
                       const float* __restrict__ dinv, int* __restrict__ cursor,
                       int2* __restrict__ adjw, int E) {
    int e = blockIdx.x * blockDim.x + threadIdx.x;
    if (e < E) {
        int r = rows[e];
        int c = cols[e];
        int pos = atomicAdd(&cursor[c], 1);
        adjw[pos] = make_int2(r, __float_as_int(dinv[r] * dinv[c]));
    }
}

// ---------------- W pack: fragment-order bf16 ----------------
__global__ void k_wpack(const float* __restrict__ W, unsigned short* __restrict__ Wp) {
    int e = blockIdx.x * 256 + threadIdx.x;   // 0..16383
    int j  = e & 7;
    int L  = (e >> 3) & 63;
    int kk = (e >> 9) & 3;
    int ct = e >> 11;
    int k = kk * 32 + (L >> 4) * 8 + j;
    int c = ct * 16 + (L & 15);
    Wp[e] = f2bf(W[k * DIM + c]);
}

// ---------------- MFMA GEMM: H(bf16) = A @ W ----------------
template <bool A_IS_F32>
__global__ __launch_bounds__(256) void k_gemm(const void* __restrict__ Ain,
                                              const unsigned short* __restrict__ Wp,
                                              unsigned short* __restrict__ H, int n) {
    __shared__ __align__(16) unsigned short As[64][136];
    const int t = threadIdx.x;
    const int wid = t >> 6, lane = t & 63;
    const int wy = wid & 1, wx = wid >> 1;
    const int base = blockIdx.x * 64;

    short8 Bf[4][4];
    {
        const short8* wp8 = (const short8*)Wp;
#pragma unroll
        for (int tt = 0; tt < 4; ++tt)
#pragma unroll
            for (int kk = 0; kk < 4; ++kk)
                Bf[tt][kk] = wp8[(((wx * 4 + tt) * 4 + kk) * 64) + lane];
    }

    if constexpr (A_IS_F32) {
        const float* A = (const float*)Ain;
#pragma unroll
        for (int it = 0; it < 8; ++it) {
            int idx = it * 256 + t;
            int row = idx >> 5, seg = idx & 31;
            int r = base + row;
            float4 v = make_float4(0.f, 0.f, 0.f, 0.f);
            if (r < n) v = ((const float4*)(A + (size_t)r * DIM))[seg];
            ushort4 o;
            o.x = f2bf(v.x); o.y = f2bf(v.y); o.z = f2bf(v.z); o.w = f2bf(v.w);
            *((ushort4*)&As[row][seg * 4]) = o;
        }
    } else {
        const unsigned short* A = (const unsigned short*)Ain;
#pragma unroll
        for (int it = 0; it < 4; ++it) {
            int idx = it * 256 + t;
            int row = idx >> 4, seg = idx & 15;
            int r = base + row;
            uint4 v = make_uint4(0, 0, 0, 0);
            if (r < n) v = ((const uint4*)(A + (size_t)r * DIM))[seg];
            *((uint4*)&As[row][seg * 8]) = v;
        }
    }
    __syncthreads();

    floatx4 acc[2][4];
#pragma unroll
    for (int rs = 0; rs < 2; ++rs)
#pragma unroll
        for (int tt = 0; tt < 4; ++tt) acc[rs][tt] = (floatx4){0.f, 0.f, 0.f, 0.f};

    const int m = lane & 15, q = lane >> 4;
#pragma unroll
    for (int rs = 0; rs < 2; ++rs) {
        const int rbase = wy * 32 + rs * 16 + m;
        short8 Af[4];
#pragma unroll
        for (int kk = 0; kk < 4; ++kk)
            Af[kk] = *((const short8*)&As[rbase][kk * 32 + q * 8]);
#pragma unroll
        for (int kk = 0; kk < 4; ++kk)
#pragma unroll
            for (int tt = 0; tt < 4; ++tt)
                acc[rs][tt] = __builtin_amdgcn_mfma_f32_16x16x32_bf16(Af[kk], Bf[tt][kk],
                                                                     acc[rs][tt], 0, 0, 0);
    }
    __syncthreads();

#pragma unroll
    for (int rs = 0; rs < 2; ++rs)
#pragma unroll
        for (int tt = 0; tt < 4; ++tt) {
            const int col = wx * 64 + tt * 16 + m;
            const int rowb = wy * 32 + rs * 16 + q * 4;
#pragma unroll
            for (int i = 0; i < 4; ++i)
                As[rowb + i][col] = f2bf(acc[rs][tt][i]);
        }
    __syncthreads();
#pragma unroll
    for (int it = 0; it < 4; ++it) {
        int idx = it * 256 + t;
        int row = idx >> 4, seg = idx & 15;
        int r = base + row;
        if (r < n)
            ((uint4*)(H + (size_t)r * DIM))[seg] = *((const uint4*)&As[row][seg * 8]);
    }
}

// ---------------- CSR aggregation (self-loop + bias + ELU), wave per node ----------------
// POOL variant: grid-stride, accumulate pooled sum per block instead of writing AGG.
template <bool POOL>
__global__ __launch_bounds__(256) void k_agg(const unsigned short* __restrict__ H,
                                             const int* __restrict__ offsets,
                                             const int2* __restrict__ adjw,
                                             const float* __restrict__ dinv,
                                             const float* __restrict__ b,
                                             unsigned short* __restrict__ AGG,
                                             float* __restrict__ partials, int n) {
    const int lane = threadIdx.x & 63;
    const int wib = threadIdx.x >> 6;
    const int wid0 = (blockIdx.x * blockDim.x + threadIdx.x) >> 6;
    const int nw = (gridDim.x * blockDim.x) >> 6;
    const float2 bb = ((const float2*)b)[lane];
    float pax = 0.f, pay = 0.f;

    for (int c = wid0; c < n; c += nw) {
        float s = dinv[c];
        s = s * s;
        unsigned int hv = *(const unsigned int*)(H + (size_t)c * DIM + lane * 2);
        float ax = bb.x + bflo(hv) * s;
        float ay = bb.y + bfhi(hv) * s;
        int j = offsets[c];
        const int end = offsets[c + 1];
        for (; j + 3 < end; j += 4) {
            int2 e0 = adjw[j], e1 = adjw[j + 1], e2 = adjw[j + 2], e3 = adjw[j + 3];
            unsigned int v0 = *(const unsigned int*)(H + (size_t)e0.x * DIM + lane * 2);
            unsigned int v1 = *(const unsigned int*)(H + (size_t)e1.x * DIM + lane * 2);
            unsigned int v2 = *(const unsigned int*)(H + (size_t)e2.x * DIM + lane * 2);
            unsigned int v3 = *(const unsigned int*)(H + (size_t)e3.x * DIM + lane * 2);
            float w0 = __int_as_float(e0.y), w1 = __int_as_float(e1.y);
            float w2 = __int_as_float(e2.y), w3 = __int_as_float(e3.y);
            ax += bflo(v0) * w0 + bflo(v1) * w1 + bflo(v2) * w2 + bflo(v3) * w3;
            ay += bfhi(v0) * w0 + bfhi(v1) * w1 + bfhi(v2) * w2 + bfhi(v3) * w3;
        }
        for (; j < end; ++j) {
            int2 e = adjw[j];
            unsigned int v = *(const unsigned int*)(H + (size_t)e.x * DIM + lane * 2);
            float w = __int_as_float(e.y);
            ax += bflo(v) * w;
            ay += bfhi(v) * w;
        }
        // ELU fused at store
        ax = ax > 0.f ? ax : expf(ax) - 1.f;
        ay = ay > 0.f ? ay : expf(ay) - 1.f;
        if (POOL) {
            pax += ax;
            pay += ay;
        } else {
            unsigned int outv = (unsigned int)f2bf(ax) | ((unsigned int)f2bf(ay) << 16);
            *(unsigned int*)(AGG + (size_t)c * DIM + lane * 2) = outv;
        }
    }

    if (POOL) {
        __shared__ float ps[4][DIM];
        ps[wib][lane * 2] = pax;
        ps[wib][lane * 2 + 1] = pay;
        __syncthreads();
        const int t = threadIdx.x;
        if (t < DIM) {
            float v = ps[0][t] + ps[1][t] + ps[2][t] + ps[3][t];
            partials[blockIdx.x * DIM + t] = v;
        }
    }
}

// ---------------- reduce block partials: pooled[d] = sum_b partials[b][d] ----------------
__global__ void k_pool2(const float* __restrict__ partials, float* __restrict__ pooled) {
    const int d = blockIdx.x;           // 128 blocks, one per dim
    float acc = 0.f;
    for (int bk = threadIdx.x; bk < PBLK; bk += 64)
        acc += partials[bk * DIM + d];
#pragma unroll
    for (int off = 32; off; off >>= 1) acc += __shfl_down(acc, off, 64);
    if (threadIdx.x == 0) pooled[d] = acc;
}

__global__ void k_final(const float* __restrict__ pooled, const float* __restrict__ lw,
                        const float* __restrict__ lb, float* __restrict__ out) {
    int o = threadIdx.x;
    if (o < 24) {
        float acc = 0.f;
#pragma unroll 8
        for (int k = 0; k < DIM; ++k) acc += pooled[k] * lw[k * 24 + o];
        out[o] = acc * (1.0f / (float)NN) + lb[o];
    }
}

extern "C" void kernel_launch(void* const* d_in, const int* in_sizes, int n_in,
                              void* d_out, int out_size, void* d_ws, size_t ws_size,
                              hipStream_t stream) {
    const float* x  = (const float*)d_in[0];
    const int*   ei = (const int*)d_in[1];
    const float* W0 = (const float*)d_in[2];
    const float* b0 = (const float*)d_in[3];
    const float* W1 = (const float*)d_in[4];
    const float* b1 = (const float*)d_in[5];
    const float* W2 = (const float*)d_in[6];
    const float* b2 = (const float*)d_in[7];
    const float* lw = (const float*)d_in[8];
    const float* lb = (const float*)d_in[9];
    float* out = (float*)d_out;

    const int N = NN, E = NE;
    const int* rows = ei;        // sources (gather)
    const int* cols = ei + E;    // targets (aggregate)

    char* ws = (char*)d_ws;
    unsigned short* H   = (unsigned short*)ws;                      // 25,600,000 B
    unsigned short* AGG = (unsigned short*)(ws + 25600000);         // 25,600,000 B
    float* dinv    = (float*)(ws + 51200000);                       // 400,000 B
    float* pooled  = (float*)(ws + 51600000);                       // 512 B
    int*   offsets = (int*)(ws + 51600512);                         // 400,128 B (N+1)
    int*   cursor  = (int*)(ws + 52000640);                         // 400,000 B
    int*   segsum  = (int*)(ws + 52400640);                         // 512 B
    int2*  adjw    = (int2*)(ws + 52401152);                        // 4,800,000 B
    unsigned short* Wp0 = (unsigned short*)(ws + 57201152);         // 32,768 B each
    unsigned short* Wp1 = Wp0 + 16384;
    unsigned short* Wp2 = Wp1 + 16384;
    float* partials = (float*)(ws + 57299456);                      // 1,048,576 B

    // ---- CSR build + W packing ----
    k_zero<<<(N + 256) / 256, 256, 0, stream>>>(offsets, N + 1);
    k_count<<<(E + 255) / 256, 256, 0, stream>>>(cols, offsets, E);
    k_rsqrt<<<(N + 255) / 256, 256, 0, stream>>>(offsets, dinv, N);
    k_scan1<<<NSEG, 256, 0, stream>>>(offsets, segsum, N);
    k_scan2<<<1, 64, 0, stream>>>(segsum, offsets, N);
    k_scan3<<<NSEG, 256, 0, stream>>>(offsets, segsum, cursor, N);
    k_fill<<<(E + 255) / 256, 256, 0, stream>>>(rows, cols, dinv, cursor, adjw, E);
    k_wpack<<<64, 256, 0, stream>>>(W0, Wp0);
    k_wpack<<<64, 256, 0, stream>>>(W1, Wp1);
    k_wpack<<<64, 256, 0, stream>>>(W2, Wp2);

    const int gemm_grid = (N + 63) / 64;
    const int agg_grid = (N * 64 + 255) / 256;

    // layer 0
    k_gemm<true><<<gemm_grid, 256, 0, stream>>>((const void*)x, Wp0, H, N);
    k_agg<false><<<agg_grid, 256, 0, stream>>>(H, offsets, adjw, dinv, b0, AGG, partials, N);
    // layer 1
    k_gemm<false><<<gemm_grid, 256, 0, stream>>>((const void*)AGG, Wp1, H, N);
    k_agg<false><<<agg_grid, 256, 0, stream>>>(H, offsets, adjw, dinv, b1, AGG, partials, N);
    // layer 2 (pooling fused; AGG never written)
    k_gemm<false><<<gemm_grid, 256, 0, stream>>>((const void*)AGG, Wp2, H, N);
    k_agg<true><<<PBLK, 256, 0, stream>>>(H, offsets, adjw, dinv, b2, AGG, partials, N);

    k_pool2<<<DIM, 64, 0, stream>>>(partials, pooled);
    k_final<<<1, 64, 0, stream>>>(pooled, lw, lb, out);
}